// Round 9
// baseline (233.978 us; speedup 1.0000x reference)
//
#include <hip/hip_runtime.h>

constexpr int Lc = 16;
constexpr int Cc = 16;
constexpr int Hc = 128;
constexpr int Wc = 256;
constexpr float DECAYc = 0.1f;
constexpr int HWc = Hc * Wc;

// float -> bf16 bits, round-to-nearest-even (inputs are finite normals).
__device__ inline unsigned short f2bf(float f) {
    unsigned int u = __float_as_uint(f);
    u += 0x7fffu + ((u >> 16) & 1u);
    return (unsigned short)(u >> 16);
}
// packed uint (bf16 pair) -> 2 floats
__device__ inline float2 bf2f2(unsigned int u) {
    return make_float2(__uint_as_float(u << 16),
                       __uint_as_float(u & 0xffff0000u));
}

// ---------------------------------------------------------------------------
// Kernel 1: transpose+convert img (L,C,H,W) f32 -> imgTb (L,H,W,C) bf16.
// (unchanged)
// ---------------------------------------------------------------------------
__global__ __launch_bounds__(256) void transpose_cvt_bf16(
    const float* __restrict__ img, unsigned short* __restrict__ imgTb)
{
    const int tid = threadIdx.x;
    const int h2 = tid & 1;
    const int wq = tid >> 1;             // 0..127
    const int kf  = blockIdx.x >> 5;     // 0..15
    const int px0 = (blockIdx.x & 31) * 1024;
    const float* __restrict__ srcb = img + (size_t)kf * Cc * HWc + (size_t)(8 * h2) * HWc;
#pragma unroll
    for (int rr = 0; rr < 8; ++rr) {
        const int px = px0 + rr * 128 + wq;
        float v[8];
#pragma unroll
        for (int c = 0; c < 8; ++c) v[c] = srcb[c * HWc + px];
        uint4 o;
        o.x = (unsigned int)f2bf(v[0]) | ((unsigned int)f2bf(v[1]) << 16);
        o.y = (unsigned int)f2bf(v[2]) | ((unsigned int)f2bf(v[3]) << 16);
        o.z = (unsigned int)f2bf(v[4]) | ((unsigned int)f2bf(v[5]) << 16);
        o.w = (unsigned int)f2bf(v[6]) | ((unsigned int)f2bf(v[7]) << 16);
        *(uint4*)(imgTb + ((size_t)kf * HWc + px) * Cc + 8 * h2) = o;
    }
}

// 8-channel FMA-accumulate of one 16B bf16 record slice.
__device__ __forceinline__ void accum8(float* a, uint4 v, float w) {
    const float2 f01 = bf2f2(v.x);
    const float2 f23 = bf2f2(v.y);
    const float2 f45 = bf2f2(v.z);
    const float2 f67 = bf2f2(v.w);
    a[0] += w * f01.x;  a[1] += w * f01.y;
    a[2] += w * f23.x;  a[3] += w * f23.y;
    a[4] += w * f45.x;  a[5] += w * f45.y;
    a[6] += w * f67.x;  a[7] += w * f67.y;
}

// ---------------------------------------------------------------------------
// Static t-slot helpers. T is a COMPILE-TIME t value (T==0 -> dead slot:
// t=0 never gathers since t>k is false for all k>=0). All ld/weight state
// is per-slot named registers -> no sparse arrays, no spill (round-6 trap).
// Px/Qx pixel-unit form validated for correctness in round 6 (absmax same).
// x-wrap folded into &255 (bit-exact, validated round 2).
// ---------------------------------------------------------------------------
template <int T>
__device__ __forceinline__ void slot_prolog(
    const float* __restrict__ cum_flow, int pix, float base_x, float base_y,
    float& Px, float& Py)
{
    if (T > 0) {
        Px = (base_x + 1.0f + cum_flow[(T * 2 + 0) * HWc + pix]) * (Wc * 0.5f) - 0.5f;
        Py = (base_y + 1.0f + cum_flow[(T * 2 + 1) * HWc + pix]) * (Hc * 0.5f) - 0.5f;
    } else { Px = 0.f; Py = 0.f; }
}

template <int T>
__device__ __forceinline__ void slot_issue(
    int k, const unsigned short* __restrict__ bk,
    float Px, float Py, float Qx, float Qy,
    float& wx, float& wy, uint4* ld)
{
    if (T > 0) if (T > k) {
        const float ix = Px - Qx;
        const float iy = Py - Qy;
        const float x0f = floorf(ix);
        const float y0f = floorf(iy);
        wx = ix - x0f;
        wy = iy - y0f;
        const int x0 = (int)x0f;
        const int y0 = (int)y0f;
        const int x0r = x0 & (Wc - 1);
        const int x1r = (x0 + 1) & (Wc - 1);
        const int y0c = min(max(y0, 0), Hc - 1);
        const int y1c = min(max(y0 + 1, 0), Hc - 1);
        ld[0] = *(const uint4*)(bk + (size_t)(y0c * Wc + x0r) * Cc);
        ld[1] = *(const uint4*)(bk + (size_t)(y0c * Wc + x1r) * Cc);
        ld[2] = *(const uint4*)(bk + (size_t)(y1c * Wc + x0r) * Cc);
        ld[3] = *(const uint4*)(bk + (size_t)(y1c * Wc + x1r) * Cc);
    }
}

template <int T>
__device__ __forceinline__ void slot_consume(
    int k, const float* __restrict__ wtab,
    float wx, float wy, const uint4* ld, float* acc)
{
    if (T > 0) if (T > k) {
        const float wkt = wtab[T * Lc + k];
        const float wb = wkt * wy;
        const float wa = wkt - wb;
        const float omx = 1.0f - wx;
        accum8(acc, ld[0], wa * omx);
        accum8(acc, ld[1], wa * wx);
        accum8(acc, ld[2], wb * omx);
        accum8(acc, ld[3], wb * wx);
    }
}

template <int T>
__device__ __forceinline__ void slot_epilog(
    const float* __restrict__ imgH, float* __restrict__ outH, int pix,
    const float* acc)
{
    const float* __restrict__ ip = imgH + (size_t)T * Cc * HWc + pix;
    float* __restrict__ op = outH + (size_t)T * Cc * HWc + pix;
#pragma unroll
    for (int c = 0; c < 8; ++c)
        op[c * HWc] = acc[c] + ip[c * HWc];
}

// ---------------------------------------------------------------------------
// One t-quarter (static T0>T1>T2>T3, T3 may be 0 = identity-only) for one
// (pixel, channel-half) lane. Rolling schedule per k:
//   issue0; issue1; consume0; issue2; consume1; issue3; flow(k+1);
//   consume2; consume3
// -> ONE true latency wait per k (consume0); later consumes run under the
// next slot's in-flight loads; flow for k+1 hides under consume2/3.
// (Round 5 had 2 serial fences + a flow load-use stall per k = ~45 exposed
// latency events/wave; this has ~KMAX.)
// ---------------------------------------------------------------------------
template <int T0, int T1, int T2, int T3>
__device__ __forceinline__ void run_quarter(
    const unsigned short* __restrict__ imgTbH,
    const float* __restrict__ cum_flow,
    const float* __restrict__ imgH,
    float* __restrict__ outH,
    const float* wtab,
    int pix, float base_x, float base_y)
{
    float Px0, Py0, Px1, Py1, Px2, Py2, Px3, Py3;
    slot_prolog<T0>(cum_flow, pix, base_x, base_y, Px0, Py0);
    slot_prolog<T1>(cum_flow, pix, base_x, base_y, Px1, Py1);
    slot_prolog<T2>(cum_flow, pix, base_x, base_y, Px2, Py2);
    slot_prolog<T3>(cum_flow, pix, base_x, base_y, Px3, Py3);

    float acc0[8], acc1[8], acc2[8], acc3[8];
#pragma unroll
    for (int c = 0; c < 8; ++c) { acc0[c] = 0.f; acc1[c] = 0.f; acc2[c] = 0.f; acc3[c] = 0.f; }

    // flow for k=0
    float fx = cum_flow[0 * HWc + pix];
    float fy = cum_flow[1 * HWc + pix];

    for (int k = 0; k < T0; ++k) {
        const unsigned short* __restrict__ bk = imgTbH + (size_t)k * HWc * Cc;
        const float Qx = fx * (Wc * 0.5f);
        const float Qy = fy * (Hc * 0.5f);

        float wx0, wy0, wx1, wy1, wx2, wy2, wx3, wy3;
        uint4 ld0[4], ld1[4], ld2[4], ld3[4];

        slot_issue<T0>(k, bk, Px0, Py0, Qx, Qy, wx0, wy0, ld0);
        slot_issue<T1>(k, bk, Px1, Py1, Qx, Qy, wx1, wy1, ld1);
        slot_consume<T0>(k, wtab, wx0, wy0, ld0, acc0);
        slot_issue<T2>(k, bk, Px2, Py2, Qx, Qy, wx2, wy2, ld2);
        slot_consume<T1>(k, wtab, wx1, wy1, ld1, acc1);
        slot_issue<T3>(k, bk, Px3, Py3, Qx, Qy, wx3, wy3, ld3);
        // prefetch next k's flow (k+1 <= 15 always in-bounds: L=16 planes)
        const float nfx = cum_flow[((k + 1) * 2 + 0) * HWc + pix];
        const float nfy = cum_flow[((k + 1) * 2 + 1) * HWc + pix];
        slot_consume<T2>(k, wtab, wx2, wy2, ld2, acc2);
        slot_consume<T3>(k, wtab, wx3, wy3, ld3, acc3);

        fx = nfx; fy = nfy;
    }

    // Epilogue: add exact fp32 identity sample (t==k, weight 1) and store.
    slot_epilog<T0>(imgH, outH, pix, acc0);
    slot_epilog<T1>(imgH, outH, pix, acc1);
    slot_epilog<T2>(imgH, outH, pix, acc2);
    slot_epilog<T3>(imgH, outH, pix, acc3);
}

// ---------------------------------------------------------------------------
// Kernel 2: EXACT round-5 mapping (best: 76us) + static-slot rolling k-body.
// Block = 32 px x 2 ch-halves x 4 waves; wave id (tid>>6) picks a t-quarter
// {15,8,5,2} {14,9,6,1} {13,10,4,3} {12,11,7,0} (30 (k,t)-pairs each).
// Round-8 lesson: the (px, half) LANE PAIRING is load-bearing — both 16B
// halves of a record are adjacent lanes (one contiguous 32B access, time-
// coincident); splitting halves across blocks doubled L2 misses (FETCH
// 100->156MB) and regressed 76->134us. Do not touch the lane map.
// 1024 blocks = 4/CU x 4 waves = 16 waves/CU; band = b&7 -> XCD.
// ---------------------------------------------------------------------------
__global__ __launch_bounds__(256, 4) void gridsample_bf16_roll(
    const unsigned short* __restrict__ imgTb,  // (L, H, W, C) bf16
    const float* __restrict__ cum_flow,        // (L, 2, H, W)
    const float* __restrict__ mask,            // (L, L)
    const float* __restrict__ decay,           // (L, L)
    const float* __restrict__ img,             // (L, C, H, W) f32, identity
    float* __restrict__ out)                   // (L, C, H, W)
{
    __shared__ float wtab[Lc * Lc];
    const int tid = threadIdx.x;
    if (tid < Lc * Lc)
        wtab[tid] = mask[tid] * __expf(-DECAYc * decay[tid]);
    __syncthreads();

    const int half = tid & 1;            // channel half: 8*half .. 8*half+7
    const int px32 = (tid >> 1) & 31;    // pixel within block
    const int wv   = tid >> 6;           // wave id = t-quarter
    const int b    = blockIdx.x;         // 0..1023
    const int band = b & 7;              // XCD id under modulo dispatch
    const int sub  = b >> 3;             // 0..127 within band
    const int h = band * 16 + (sub >> 3);
    const int w = (sub & 7) * 32 + px32;
    const int pix = h * Wc + w;

    const float base_x = w * (2.0f / Wc) - 1.0f + 1.0f / Wc;
    const float base_y = h * (2.0f / Hc) - 1.0f + 1.0f / Hc;

    // wave-uniform half-offsets folded into base pointers
    const unsigned short* __restrict__ imgTbH = imgTb + 8 * half;          // +16B
    const float* __restrict__ imgH = img + (size_t)(8 * half) * HWc;
    float* __restrict__ outH = out + (size_t)(8 * half) * HWc;

    switch (wv) {
        case 0:  run_quarter<15, 8, 5, 2>(imgTbH, cum_flow, imgH, outH, wtab, pix, base_x, base_y); break;
        case 1:  run_quarter<14, 9, 6, 1>(imgTbH, cum_flow, imgH, outH, wtab, pix, base_x, base_y); break;
        case 2:  run_quarter<13, 10, 4, 3>(imgTbH, cum_flow, imgH, outH, wtab, pix, base_x, base_y); break;
        default: run_quarter<12, 11, 7, 0>(imgTbH, cum_flow, imgH, outH, wtab, pix, base_x, base_y); break;
    }
}

// ---------------------------------------------------------------------------
// Fallback (Round-1 kernel): used only if ws_size is too small.
// ---------------------------------------------------------------------------
__global__ __launch_bounds__(256) void gridsample_warp_acc(
    const float* __restrict__ img, const float* __restrict__ cum_flow,
    const float* __restrict__ mask, const float* __restrict__ decay,
    float* __restrict__ out)
{
    const int w = threadIdx.x, h = blockIdx.x, t = blockIdx.y;
    const int pix = h * Wc + w;
    const float base_x = w * (2.0f / Wc) - 1.0f + 1.0f / Wc;
    const float base_y = h * (2.0f / Hc) - 1.0f + 1.0f / Hc;
    const float fxt = cum_flow[(t * 2 + 0) * HWc + pix];
    const float fyt = cum_flow[(t * 2 + 1) * HWc + pix];
    float acc[Cc];
#pragma unroll
    for (int c = 0; c < Cc; ++c) acc[c] = 0.0f;
    for (int k = 0; k <= t; ++k) {
        const float wkt = mask[t * Lc + k] * __expf(-DECAYc * decay[t * Lc + k]);
        const float fxk = cum_flow[(k * 2 + 0) * HWc + pix];
        const float fyk = cum_flow[(k * 2 + 1) * HWc + pix];
        float gx = base_x + (fxt - fxk);
        const float gy = base_y + (fyt - fyk);
        float m = gx + 1.0f;
        m -= 2.0f * floorf(m * 0.5f);
        gx = m - 1.0f;
        const float ix = (gx + 1.0f) * (Wc * 0.5f) - 0.5f;
        const float iy = (gy + 1.0f) * (Hc * 0.5f) - 0.5f;
        const float x0f = floorf(ix), y0f = floorf(iy);
        const float wx = ix - x0f, wy = iy - y0f;
        const int x0 = (int)x0f, y0 = (int)y0f;
        const int x0r = x0 & (Wc - 1), x1r = (x0 + 1) & (Wc - 1);
        const int y0c = min(max(y0, 0), Hc - 1), y1c = min(max(y0 + 1, 0), Hc - 1);
        const float a00 = wkt * (1.0f - wx) * (1.0f - wy);
        const float a01 = wkt * (1.0f - wx) * wy;
        const float a10 = wkt * wx * (1.0f - wy);
        const float a11 = wkt * wx * wy;
        const int o00 = y0c * Wc + x0r, o01 = y1c * Wc + x0r;
        const int o10 = y0c * Wc + x1r, o11 = y1c * Wc + x1r;
        const float* __restrict__ ik = img + (size_t)k * Cc * HWc;
#pragma unroll
        for (int c = 0; c < Cc; ++c) {
            const float* __restrict__ p = ik + c * HWc;
            acc[c] += p[o00] * a00 + p[o01] * a01 + p[o10] * a10 + p[o11] * a11;
        }
    }
    float* __restrict__ op = out + (size_t)t * Cc * HWc + pix;
#pragma unroll
    for (int c = 0; c < Cc; ++c) op[c * HWc] = acc[c];
}

extern "C" void kernel_launch(void* const* d_in, const int* in_sizes, int n_in,
                              void* d_out, int out_size, void* d_ws, size_t ws_size,
                              hipStream_t stream) {
    const float* img      = (const float*)d_in[0];
    const float* cum_flow = (const float*)d_in[1];
    const float* mask     = (const float*)d_in[2];
    const float* decay    = (const float*)d_in[3];
    float* out = (float*)d_out;

    const size_t needed = (size_t)Lc * HWc * Cc * sizeof(unsigned short);  // 16 MB
    if (ws_size >= needed) {
        unsigned short* imgTb = (unsigned short*)d_ws;
        transpose_cvt_bf16<<<dim3(512), 256, 0, stream>>>(img, imgTb);
        gridsample_bf16_roll<<<dim3(1024), 256, 0, stream>>>(
            imgTb, cum_flow, mask, decay, img, out);
    } else {
        dim3 grid(Hc, Lc, 1);
        gridsample_warp_acc<<<grid, Wc, 0, stream>>>(img, cum_flow, mask, decay, out);
    }
}